// Round 11
// baseline (98.076 us; speedup 1.0000x reference)
//
#include <hip/hip_runtime.h>
#include <cstdint>
#include <cstddef>

typedef __attribute__((ext_vector_type(8))) short short8v;
typedef __attribute__((ext_vector_type(4))) unsigned uint4v;
typedef __attribute__((ext_vector_type(4))) float floatx4;

#define LIN 568   // weight row length: 1 + 9*63

__device__ __forceinline__ short f32_to_bf16(float f) {
  unsigned u = __builtin_bit_cast(unsigned, f);
  u += 0x7fffu + ((u >> 16) & 1u);   // RNE (inputs finite)
  return (short)(u >> 16);
}
__device__ __forceinline__ float bf16_to_f32(short s) {
  return __builtin_bit_cast(float, ((unsigned)(unsigned short)s) << 16);
}
// Packed RNE f32->bf16 (2 values / instruction), bitwise-identical to manual RNE.
__device__ __forceinline__ unsigned cvt_pk_bf16(float lo, float hi) {
  unsigned r;
  asm("v_cvt_pk_bf16_f32 %0, %1, %2" : "=v"(r) : "v"(lo), "v"(hi));
  return r;
}
// Cross-lane add via DPP (pure VALU, no ds op).
template<int CTRL>
__device__ __forceinline__ float dpp_add(float v) {
  int y = __builtin_amdgcn_update_dpp(0, __builtin_bit_cast(int, v), CTRL, 0xF, 0xF, true);
  return v + __builtin_bit_cast(float, y);
}

// Pack weight into MFMA-B-fragment-major order (bf16):
//   wfragg[step*2048 + nb*512 + lane*8 + j]
//     = W[n = nb*16 + (lane&15)][k = tap*64 + half*32 + (lane>>4)*8 + j]
// Steps 18..19 zero-padded (K-loop B-prefetch tail reads them harmlessly).
__global__ void prep_weight(const float* __restrict__ w, short* __restrict__ wfragg) {
  int i = blockIdx.x * 256 + threadIdx.x;   // 0 .. 40959
  if (i >= 20 * 2048) return;
  if (i >= 9 * 2 * 4 * 64 * 8) { wfragg[i] = 0; return; }
  int j    = i & 7;
  int lane = (i >> 3) & 63;
  int nb   = (i >> 9) & 3;
  int half = (i >> 11) & 1;
  int tap  = i >> 12;
  int n = nb * 16 + (lane & 15);
  int c = half * 32 + ((lane >> 4) << 3) + j;
  float v = (c == 0) ? 0.0f : w[n * LIN + 1 + tap * 63 + (c - 1)];
  wfragg[i] = f32_to_bf16(v);
}

// COMPACT-CODE version of the R8 champion. Identical dataflow/addressing;
// the 18 MFMA steps are a ROLLED loop over taps (t=0..8, 2 half-steps/iter),
// staging is a rolled loop, so the whole kernel is ~7KB of code (vs ~40-60KB
// fully unrolled) and fits the 32KB L1I -> no instruction-fetch streaming,
// which the 11-round ledger indicates is the invariant ~42us floor:
// all pipes <20%, duration invariant to data-cache state / occupancy /
// staging method / store pattern, and the only wins came from code removal.
__launch_bounds__(256, 2)
__global__ void lconv_main(const float* __restrict__ x, const float* __restrict__ w,
                           const float* __restrict__ bias, const short* __restrict__ wfragg,
                           float* __restrict__ out) {
  // 66560 B: short xt[6*66*72] (57024 B) during compute, then aliased as
  // float ostg[4][4160] for the store-staging epilogue.
  __shared__ __align__(16) char shmem[4 * 4160 * 4];
  __shared__ float tres_s[4 * 64];    // per-wave time-feature row (1 KB)
  short* xt = (short*)shmem;

  const int tid = threadIdx.x;
  const int bb = blockIdx.x >> 4;          // batch 0..31
  const int h0 = (blockIdx.x & 15) << 2;   // first output row of 4-row strip
  const float* xb = x + (size_t)bb * (64 * 64 * 64);

  const int lane = tid & 63;
  const int l15 = lane & 15;
  const int q = lane >> 4;
  const int wv = tid >> 6;   // wave id = strip row

  // ---- staging: rolled loop, rows 0..5 (x rows h0-1..h0+4), 8 loads in flight ----
#pragma unroll 1
  for (int g = 0; g < 3; ++g) {
#pragma unroll
    for (int k = 0; k < 4; ++k) {
      int idx = (g * 4 + k) * 256 + tid;   // 0..3071 : rows 0..5 x 64 cols x 8 ch8-groups
      int row = idx >> 9;
      int rem = idx & 511;
      int col = rem >> 3;
      int ch8 = (rem & 7) << 3;
      int h = h0 - 1 + row;
      float4 v0 = {0.f, 0.f, 0.f, 0.f}, v1 = {0.f, 0.f, 0.f, 0.f};
      if ((unsigned)h < 64u) {
        const float* p = xb + ((h * 64 + col) * 64 + ch8);
        v0 = *(const float4*)p;
        v1 = *(const float4*)(p + 4);
      }
      uint4v o;
      o[0] = cvt_pk_bf16(v0.x, v0.y);
      o[1] = cvt_pk_bf16(v0.z, v0.w);
      o[2] = cvt_pk_bf16(v1.x, v1.y);
      o[3] = cvt_pk_bf16(v1.z, v1.w);
      *(uint4v*)&xt[(row * 66 + col + 1) * 72 + ch8] = o;
    }
  }
  if (tid < 96) {   // pads: rows 0..5, cols 0 and 65
    int r = tid >> 4;
    int cc = (tid >> 3) & 1;
    int ch8 = (tid & 7) << 3;
    short8v z = {0, 0, 0, 0, 0, 0, 0, 0};
    *(short8v*)&xt[(r * 66 + cc * 65) * 72 + ch8] = z;
  }

  // ---- B double-buffer prologue + epilogue constants ----
  const short* wfl = wfragg + lane * 8;
  short8v bA[4], bB[4];
#pragma unroll
  for (int nb = 0; nb < 4; ++nb) {
    bA[nb] = *(const short8v*)(wfl + 0 * 2048 + nb * 512);
    bB[nb] = *(const short8v*)(wfl + 1 * 2048 + nb * 512);
  }
  float bj[4], w0j[4];
#pragma unroll
  for (int nb = 0; nb < 4; ++nb) {
    int n = nb * 16 + l15;
    bj[nb] = bias[n];
    w0j[nb] = w[n * LIN];   // weight[:,0] fp32
  }

  __syncthreads();   // whole tile visible

  floatx4 acc[4][4];
#pragma unroll
  for (int mb = 0; mb < 4; ++mb)
#pragma unroll
    for (int nb = 0; nb < 4; ++nb) acc[mb][nb] = floatx4{0.f, 0.f, 0.f, 0.f};

  // ---- rolled K-loop: t = tap 0..8; two half-steps (K=32 each) per iteration ----
#pragma unroll 1
  for (int t = 0; t < 9; ++t) {
    const int kh = (t * 11) >> 5;      // t/3 for t in 0..8
    const int kw = t - 3 * kh;         // t%3
    const short* ab = &xt[((wv + kh) * 66 + kw + l15) * 72 + q * 8];   // half=0 base
    const short8v z = {0, 0, 0, 0, 0, 0, 0, 0};

    // -- half 0: use bA, then reload bA = B(2t+2) (in flight across half 1) --
    short8v a[4];
#pragma unroll
    for (int mb = 0; mb < 4; ++mb)
      a[mb] = *(const short8v*)(ab + mb * 16 * 72);
    if (kw == 0 && l15 == 0)  a[0] = z;   // col -1 (left pad)
    if (kw == 2 && l15 == 15) a[3] = z;   // col 64 (right pad)
#pragma unroll
    for (int mb = 0; mb < 4; ++mb)
#pragma unroll
      for (int nb = 0; nb < 4; ++nb)
        acc[mb][nb] = __builtin_amdgcn_mfma_f32_16x16x32_bf16(a[mb], bA[nb], acc[mb][nb], 0, 0, 0);
#pragma unroll
    for (int nb = 0; nb < 4; ++nb)
      bA[nb] = *(const short8v*)(wfl + (2 * t + 2) * 2048 + nb * 512);   // t=8: zero pad rows

    // -- half 1: use bB, then reload bB = B(2t+3) --
#pragma unroll
    for (int mb = 0; mb < 4; ++mb)
      a[mb] = *(const short8v*)(ab + 32 + mb * 16 * 72);
    if (kw == 0 && l15 == 0)  a[0] = z;
    if (kw == 2 && l15 == 15) a[3] = z;
#pragma unroll
    for (int mb = 0; mb < 4; ++mb)
#pragma unroll
      for (int nb = 0; nb < 4; ++nb)
        acc[mb][nb] = __builtin_amdgcn_mfma_f32_16x16x32_bf16(a[mb], bB[nb], acc[mb][nb], 0, 0, 0);
#pragma unroll
    for (int nb = 0; nb < 4; ++nb)
      bB[nb] = *(const short8v*)(wfl + (2 * t + 3) * 2048 + nb * 512);   // t=8: zero pad rows
  }

  // ---- per-pixel time feature (this wave's row; lane <-> pixel col) ----
  {
    float ss = 0.f;
#pragma unroll
    for (int dh = 0; dh < 3; ++dh)
#pragma unroll
      for (int dw = 0; dw < 3; ++dw) {
        float tv = bf16_to_f32(xt[((wv + dh) * 66 + lane + dw) * 72]);
        tv = fmaxf(tv, 1.0f);
        ss += tv * tv;
      }
    tres_s[wv * 64 + lane] = sqrtf(ss - 8.0f);   // same-wave producer/consumer
  }

  __syncthreads();   // last xt read done (all waves) -> safe to alias as ostg

  // ---- epilogue: bias + rank-1 time term, Lorentz norm (DPP), scatter to LDS ----
  float* ostg = (float*)shmem + wv * 4160;   // this wave's 64px x 65ch row image
#pragma unroll
  for (int mb = 0; mb < 4; ++mb) {
    float4 t4 = *(const float4*)&tres_s[wv * 64 + mb * 16 + q * 4];
#pragma unroll
    for (int r = 0; r < 4; ++r) {
      int pcol = mb * 16 + q * 4 + r;      // C/D row m = quad*4 + reg
      float tr = t4[r];
      float v0 = acc[mb][0][r] + bj[0] + tr * w0j[0];
      float v1 = acc[mb][1][r] + bj[1] + tr * w0j[1];
      float v2 = acc[mb][2][r] + bj[2] + tr * w0j[2];
      float v3 = acc[mb][3][r] + bj[3] + tr * w0j[3];
      float ss = v0 * v0 + v1 * v1 + v2 * v2 + v3 * v3;
      ss = dpp_add<0xB1>(ss);    // + lane^1
      ss = dpp_add<0x4E>(ss);    // + lane^2
      ss = dpp_add<0x141>(ss);   // + mirror-8
      ss = dpp_add<0x140>(ss);   // + mirror-16 (full 16-lane sum)
      float* pb = ostg + pcol * 65;
      if (l15 == 0) pb[0] = sqrtf(ss + 1.0f);
      pb[1 + l15]  = v0;
      pb[17 + l15] = v1;
      pb[33 + l15] = v2;
      pb[49 + l15] = v3;
    }
  }

  // ---- coalesced flush: LDS row image -> global (dense dwordx4) ----
  {
    float* orow = out + (size_t)((bb * 64 + h0 + wv) * 64) * 65;
#pragma unroll 1
    for (int it = 0; it < 16; ++it) {
      int off = it * 256 + lane * 4;
      *(float4*)(orow + off) = *(const float4*)(ostg + off);
    }
    if (lane < 16) {   // remainder: 4160 - 4096 = 64 floats
      int off = 4096 + lane * 4;
      *(float4*)(orow + off) = *(const float4*)(ostg + off);
    }
  }
}

extern "C" void kernel_launch(void* const* d_in, const int* in_sizes, int n_in,
                              void* d_out, int out_size, void* d_ws, size_t ws_size,
                              hipStream_t stream) {
  const float* x = (const float*)d_in[0];
  const float* w = (const float*)d_in[1];
  const float* b = (const float*)d_in[2];
  float* out = (float*)d_out;
  short* wfragg = (short*)d_ws;   // 81920 B fragment-packed bf16 weight (20 steps, 2 zero)

  prep_weight<<<160, 256, 0, stream>>>(w, wfragg);
  lconv_main<<<32 * 16, 256, 0, stream>>>(x, w, b, wfragg, out);
}

// Round 12
// 97.954 us; speedup vs baseline: 1.0012x; 1.0012x over previous
//
#include <hip/hip_runtime.h>
#include <cstdint>
#include <cstddef>

typedef __attribute__((ext_vector_type(8))) short short8v;
typedef __attribute__((ext_vector_type(4))) unsigned uint4v;
typedef __attribute__((ext_vector_type(4))) float floatx4;

#define LIN 568   // weight row length: 1 + 9*63

__device__ __forceinline__ short f32_to_bf16(float f) {
  unsigned u = __builtin_bit_cast(unsigned, f);
  u += 0x7fffu + ((u >> 16) & 1u);   // RNE (inputs finite)
  return (short)(u >> 16);
}
__device__ __forceinline__ float bf16_to_f32(short s) {
  return __builtin_bit_cast(float, ((unsigned)(unsigned short)s) << 16);
}
// Packed RNE f32->bf16 (2 values / instruction), bitwise-identical to manual RNE.
__device__ __forceinline__ unsigned cvt_pk_bf16(float lo, float hi) {
  unsigned r;
  asm("v_cvt_pk_bf16_f32 %0, %1, %2" : "=v"(r) : "v"(lo), "v"(hi));
  return r;
}
// Cross-lane add via DPP (pure VALU, no ds op).
template<int CTRL>
__device__ __forceinline__ float dpp_add(float v) {
  int y = __builtin_amdgcn_update_dpp(0, __builtin_bit_cast(int, v), CTRL, 0xF, 0xF, true);
  return v + __builtin_bit_cast(float, y);
}
// Register-free global->LDS 16B copy (per-lane global addr, lane-linear LDS dest).
__device__ __forceinline__ void gload_lds16(const short* g, short* lds) {
  __builtin_amdgcn_global_load_lds(
      (const __attribute__((address_space(1))) void*)g,
      (__attribute__((address_space(3))) void*)lds, 16, 0, 0);
}

// Pack weight into MFMA-B-fragment-major order (bf16):
//   wfragg[step*2048 + nb*512 + lane*8 + j]
//     = W[n = nb*16 + (lane&15)][k = tap*64 + half*32 + (lane>>4)*8 + j]
// step = tap*2 + half; c==0 column zeroed (time feature is rank-1 epilogue).
__global__ void prep_weight(const float* __restrict__ w, short* __restrict__ wfragg) {
  int i = blockIdx.x * 256 + threadIdx.x;   // 0 .. 36863
  if (i >= 9 * 2 * 4 * 64 * 8) return;
  int j    = i & 7;
  int lane = (i >> 3) & 63;
  int nb   = (i >> 9) & 3;
  int half = (i >> 11) & 1;
  int tap  = i >> 12;
  int n = nb * 16 + (lane & 15);
  int c = half * 32 + ((lane >> 4) << 3) + j;
  float v = (c == 0) ? 0.0f : w[n * LIN + 1 + tap * 63 + (c - 1)];
  wfragg[i] = f32_to_bf16(v);
}

// R8 champion + B-THROUGH-LDS: previously every wave streamed the full 73.7 KB
// wfragg from L2 (per-CU: 8 waves x 147 KB = 1.18 MB = ~8-9 us of L2 BW — the
// largest single throughput term). Now the block cooperatively stages each
// step's 4 KB B-batch into a 3-deep LDS ring via global_load_lds (issued 2
// steps ahead), and waves ds_read it: per-CU B L2-traffic drops 8x.
// Loop: vmcnt(1) -> s_barrier -> sched_barrier(0) -> issue B(s+2) -> read -> MFMA.
// (Counted vmcnt, never 0 mid-loop; buffer (s+2)%3 was last read at step s-1,
// and the issue is after barrier s, so all waves are done with it.)
__launch_bounds__(256, 2)
__global__ void lconv_main(const float* __restrict__ x, const float* __restrict__ w,
                           const float* __restrict__ bias, const short* __restrict__ wfragg,
                           float* __restrict__ out) {
  // 66560 B: short xt[6*66*72] (57024 B) during compute, then aliased as
  // float ostg[4][4160] for the store-staging epilogue.
  __shared__ __align__(16) char shmem[4 * 4160 * 4];
  __shared__ float tres_s[4 * 64];      // per-wave time-feature row (1 KB)
  __shared__ short bstg[3 * 2048];      // 12 KB: 3-deep B-batch ring (4 KB/step)
  short* xt = (short*)shmem;

  const int tid = threadIdx.x;
  const int bb = blockIdx.x >> 4;          // batch 0..31
  const int h0 = (blockIdx.x & 15) << 2;   // first output row of 4-row strip
  const float* xb = x + (size_t)bb * (64 * 64 * 64);

  const int lane = tid & 63;
  const int l15 = lane & 15;
  const int q = lane >> 4;
  const int wv = tid >> 6;   // wave id = strip row

  // ---- x staging: single phase, rows 0..5 (x rows h0-1..h0+4) ----
  float4 s0[12], s1[12];
#pragma unroll
  for (int i = 0; i < 12; ++i) {
    int idx = i * 256 + tid;       // 0..3071 : rows 0..5 x 64 cols x 8 ch8-groups
    int row = idx >> 9;
    int rem = idx & 511;
    int col = rem >> 3;
    int ch8 = (rem & 7) << 3;
    int h = h0 - 1 + row;
    s0[i] = {0.f, 0.f, 0.f, 0.f};
    s1[i] = {0.f, 0.f, 0.f, 0.f};
    if ((unsigned)h < 64u) {
      const float* p = xb + ((h * 64 + col) * 64 + ch8);
      s0[i] = *(const float4*)p;
      s1[i] = *(const float4*)(p + 4);
    }
  }
  float bj[4], w0j[4];
#pragma unroll
  for (int nb = 0; nb < 4; ++nb) {
    int n = nb * 16 + l15;
    bj[nb] = bias[n];
    w0j[nb] = w[n * LIN];   // weight[:,0] fp32
  }
#pragma unroll
  for (int i = 0; i < 12; ++i) {
    int idx = i * 256 + tid;
    int row = idx >> 9;
    int rem = idx & 511;
    int col = rem >> 3;
    int ch8 = (rem & 7) << 3;
    uint4v o;
    o[0] = cvt_pk_bf16(s0[i].x, s0[i].y);
    o[1] = cvt_pk_bf16(s0[i].z, s0[i].w);
    o[2] = cvt_pk_bf16(s1[i].x, s1[i].y);
    o[3] = cvt_pk_bf16(s1[i].z, s1[i].w);
    *(uint4v*)&xt[(row * 66 + col + 1) * 72 + ch8] = o;
  }
  if (tid < 96) {   // pads: rows 0..5, cols 0 and 65
    int r = tid >> 4;
    int cc = (tid >> 3) & 1;
    int ch8 = (tid & 7) << 3;
    short8v z = {0, 0, 0, 0, 0, 0, 0, 0};
    *(short8v*)&xt[(r * 66 + cc * 65) * 72 + ch8] = z;
  }

  // ---- issue B batches 0,1 into ring slots 0,1 (drained by the barrier below) ----
  gload_lds16(wfragg + 0 * 2048 + tid * 8, &bstg[0 * 2048 + tid * 8]);
  gload_lds16(wfragg + 1 * 2048 + tid * 8, &bstg[1 * 2048 + tid * 8]);

  __syncthreads();   // tile + B0,B1 visible (full drain, prologue only)

  floatx4 acc[4][4];
#pragma unroll
  for (int mb = 0; mb < 4; ++mb)
#pragma unroll
    for (int nb = 0; nb < 4; ++nb) acc[mb][nb] = floatx4{0.f, 0.f, 0.f, 0.f};

  auto do_step = [&](int step) {
    // batch `step` guaranteed landed after this wait (<=1 newer batch in flight)
    if (step < 17) asm volatile("s_waitcnt vmcnt(1)" ::: "memory");
    else           asm volatile("s_waitcnt vmcnt(0)" ::: "memory");
    __builtin_amdgcn_s_barrier();            // all waves done reading step-1's slot
    __builtin_amdgcn_sched_barrier(0);       // no ds_read hoisting above the barrier

    if (step + 2 < 18)                        // refill slot (step+2)%3 == (step-1)%3
      gload_lds16(wfragg + (step + 2) * 2048 + tid * 8,
                  &bstg[((step + 2) % 3) * 2048 + tid * 8]);

    const int tap = step >> 1, half = step & 1;
    const int kh = tap / 3, kw = tap % 3;

    short8v b[4];
    const short* bbp = &bstg[(step % 3) * 2048 + lane * 8];
#pragma unroll
    for (int nb = 0; nb < 4; ++nb)
      b[nb] = *(const short8v*)(bbp + nb * 512);

    const short* ab = &xt[((wv + kh) * 66 + kw + l15) * 72 + half * 32 + q * 8];
    short8v a[4];
#pragma unroll
    for (int mb = 0; mb < 4; ++mb)
      a[mb] = *(const short8v*)(ab + mb * 16 * 72);
    short8v z = {0, 0, 0, 0, 0, 0, 0, 0};
    if (kw == 0 && l15 == 0)  a[0] = z;   // col -1 (left pad)
    if (kw == 2 && l15 == 15) a[3] = z;   // col 64 (right pad)

#pragma unroll
    for (int mb = 0; mb < 4; ++mb) {
#pragma unroll
      for (int nb = 0; nb < 4; ++nb)
        acc[mb][nb] = __builtin_amdgcn_mfma_f32_16x16x32_bf16(a[mb], b[nb], acc[mb][nb], 0, 0, 0);
    }
  };

#pragma unroll
  for (int step = 0; step < 18; ++step) do_step(step);

  // ---- per-pixel time feature (this wave's row; lane <-> pixel col) ----
  {
    float ss = 0.f;
#pragma unroll
    for (int dh = 0; dh < 3; ++dh)
#pragma unroll
      for (int dw = 0; dw < 3; ++dw) {
        float tv = bf16_to_f32(xt[((wv + dh) * 66 + lane + dw) * 72]);
        tv = fmaxf(tv, 1.0f);
        ss += tv * tv;
      }
    tres_s[wv * 64 + lane] = sqrtf(ss - 8.0f);   // same-wave producer/consumer
  }

  __syncthreads();   // last xt read done (all waves) -> safe to alias as ostg

  // ---- epilogue: bias + rank-1 time term, Lorentz norm (DPP), scatter to LDS ----
  float* ostg = (float*)shmem + wv * 4160;   // this wave's 64px x 65ch row image
#pragma unroll
  for (int mb = 0; mb < 4; ++mb) {
    float4 t4 = *(const float4*)&tres_s[wv * 64 + mb * 16 + q * 4];
#pragma unroll
    for (int r = 0; r < 4; ++r) {
      int pcol = mb * 16 + q * 4 + r;      // C/D row m = quad*4 + reg
      float tr = t4[r];
      float v0 = acc[mb][0][r] + bj[0] + tr * w0j[0];
      float v1 = acc[mb][1][r] + bj[1] + tr * w0j[1];
      float v2 = acc[mb][2][r] + bj[2] + tr * w0j[2];
      float v3 = acc[mb][3][r] + bj[3] + tr * w0j[3];
      float ss = v0 * v0 + v1 * v1 + v2 * v2 + v3 * v3;
      ss = dpp_add<0xB1>(ss);    // + lane^1
      ss = dpp_add<0x4E>(ss);    // + lane^2
      ss = dpp_add<0x141>(ss);   // + mirror-8
      ss = dpp_add<0x140>(ss);   // + mirror-16 (full 16-lane sum)
      float* pb = ostg + pcol * 65;
      if (l15 == 0) pb[0] = sqrtf(ss + 1.0f);
      pb[1 + l15]  = v0;
      pb[17 + l15] = v1;
      pb[33 + l15] = v2;
      pb[49 + l15] = v3;
    }
  }

  // ---- coalesced flush: LDS row image -> global (dense dwordx4) ----
  // Same-wave produce/consume: compiler inserts the lgkmcnt wait; no barrier.
  {
    float* orow = out + (size_t)((bb * 64 + h0 + wv) * 64) * 65;
#pragma unroll
    for (int it = 0; it < 16; ++it) {
      int off = it * 256 + lane * 4;
      *(float4*)(orow + off) = *(const float4*)(ostg + off);
    }
    if (lane < 16) {   // remainder: 4160 - 4096 = 64 floats
      int off = 4096 + lane * 4;
      *(float4*)(orow + off) = *(const float4*)(ostg + off);
    }
  }
}

extern "C" void kernel_launch(void* const* d_in, const int* in_sizes, int n_in,
                              void* d_out, int out_size, void* d_ws, size_t ws_size,
                              hipStream_t stream) {
  const float* x = (const float*)d_in[0];
  const float* w = (const float*)d_in[1];
  const float* b = (const float*)d_in[2];
  float* out = (float*)d_out;
  short* wfragg = (short*)d_ws;   // 73728 B fragment-packed bf16 weight

  prep_weight<<<144, 256, 0, stream>>>(w, wfragg);
  lconv_main<<<32 * 16, 256, 0, stream>>>(x, w, b, wfragg, out);
}

// Round 13
// 97.425 us; speedup vs baseline: 1.0067x; 1.0054x over previous
//
#include <hip/hip_runtime.h>
#include <cstdint>
#include <cstddef>

typedef __attribute__((ext_vector_type(8))) short short8v;
typedef __attribute__((ext_vector_type(4))) unsigned uint4v;
typedef __attribute__((ext_vector_type(4))) float floatx4;

#define LIN 568   // weight row length: 1 + 9*63

__device__ __forceinline__ short f32_to_bf16(float f) {
  unsigned u = __builtin_bit_cast(unsigned, f);
  u += 0x7fffu + ((u >> 16) & 1u);   // RNE (inputs finite)
  return (short)(u >> 16);
}
__device__ __forceinline__ float bf16_to_f32(short s) {
  return __builtin_bit_cast(float, ((unsigned)(unsigned short)s) << 16);
}
// Packed RNE f32->bf16 (2 values / instruction), bitwise-identical to manual RNE.
__device__ __forceinline__ unsigned cvt_pk_bf16(float lo, float hi) {
  unsigned r;
  asm("v_cvt_pk_bf16_f32 %0, %1, %2" : "=v"(r) : "v"(lo), "v"(hi));
  return r;
}
// Cross-lane add via DPP (pure VALU, no ds op).
template<int CTRL>
__device__ __forceinline__ float dpp_add(float v) {
  int y = __builtin_amdgcn_update_dpp(0, __builtin_bit_cast(int, v), CTRL, 0xF, 0xF, true);
  return v + __builtin_bit_cast(float, y);
}

// Pack weight into MFMA-B-fragment-major order (bf16):
//   wfragg[step*2048 + nb*512 + lane*8 + j]
//     = W[n = nb*16 + (lane&15)][k = tap*64 + half*32 + (lane>>4)*8 + j]
// step = tap*2 + half; c==0 column zeroed (time feature is rank-1 epilogue).
__global__ void prep_weight(const float* __restrict__ w, short* __restrict__ wfragg) {
  int i = blockIdx.x * 256 + threadIdx.x;   // 0 .. 36863
  if (i >= 9 * 2 * 4 * 64 * 8) return;
  int j    = i & 7;
  int lane = (i >> 3) & 63;
  int nb   = (i >> 9) & 3;
  int half = (i >> 11) & 1;
  int tap  = i >> 12;
  int n = nb * 16 + (lane & 15);
  int c = half * 32 + ((lane >> 4) << 3) + j;
  float v = (c == 0) ? 0.0f : w[n * LIN + 1 + tap * 63 + (c - 1)];
  wfragg[i] = f32_to_bf16(v);
}

// CONSOLIDATED champion (R8 minus never-validated scaffolding):
// - x staging: ONE fused load->cvt->write unrolled loop (no T14 register
//   retention: -96 VGPR pressure, -72 duplicated addressing instructions)
// - ONE barrier before the MFMA loop (single-phase; R12 proved safe/equal)
// - 18-step unrolled MFMA loop with depth-3 B prefetch (R8 verbatim)
// - DPP Lorentz reduce + LDS-staged coalesced output flush (R8 verbatim)
__launch_bounds__(256, 2)
__global__ void lconv_main(const float* __restrict__ x, const float* __restrict__ w,
                           const float* __restrict__ bias, const short* __restrict__ wfragg,
                           float* __restrict__ out) {
  // 66560 B: short xt[6*66*72] (57024 B) during compute, then aliased as
  // float ostg[4][4160] for the store-staging epilogue.
  __shared__ __align__(16) char shmem[4 * 4160 * 4];
  __shared__ float tres_s[4 * 64];    // per-wave time-feature row (1 KB)
  short* xt = (short*)shmem;

  const int tid = threadIdx.x;
  const int bb = blockIdx.x >> 4;          // batch 0..31
  const int h0 = (blockIdx.x & 15) << 2;   // first output row of 4-row strip
  const float* xb = x + (size_t)bb * (64 * 64 * 64);

  const int lane = tid & 63;
  const int l15 = lane & 15;
  const int q = lane >> 4;
  const int wv = tid >> 6;   // wave id = strip row

  // ---- x staging: fused load+cvt+write, rows 0..5 (x rows h0-1..h0+4) ----
#pragma unroll
  for (int i = 0; i < 12; ++i) {
    int idx = i * 256 + tid;       // 0..3071 : rows 0..5 x 64 cols x 8 ch8-groups
    int row = idx >> 9;
    int rem = idx & 511;
    int col = rem >> 3;
    int ch8 = (rem & 7) << 3;
    int h = h0 - 1 + row;
    float4 v0 = {0.f, 0.f, 0.f, 0.f}, v1 = {0.f, 0.f, 0.f, 0.f};
    if ((unsigned)h < 64u) {
      const float* p = xb + ((h * 64 + col) * 64 + ch8);
      v0 = *(const float4*)p;
      v1 = *(const float4*)(p + 4);
    }
    uint4v o;
    o[0] = cvt_pk_bf16(v0.x, v0.y);
    o[1] = cvt_pk_bf16(v0.z, v0.w);
    o[2] = cvt_pk_bf16(v1.x, v1.y);
    o[3] = cvt_pk_bf16(v1.z, v1.w);
    *(uint4v*)&xt[(row * 66 + col + 1) * 72 + ch8] = o;
  }
  if (tid < 96) {   // pads: rows 0..5, cols 0 and 65
    int r = tid >> 4;
    int cc = (tid >> 3) & 1;
    int ch8 = (tid & 7) << 3;
    short8v z = {0, 0, 0, 0, 0, 0, 0, 0};
    *(short8v*)&xt[(r * 66 + cc * 65) * 72 + ch8] = z;
  }

  // ---- B fragments for steps 0..2 + epilogue constants ----
  const short* wfl = wfragg + lane * 8;
  short8v b0[4], b1[4], b2[4];
#pragma unroll
  for (int nb = 0; nb < 4; ++nb) {
    b0[nb] = *(const short8v*)(wfl + 0 * 2048 + nb * 512);
    b1[nb] = *(const short8v*)(wfl + 1 * 2048 + nb * 512);
    b2[nb] = *(const short8v*)(wfl + 2 * 2048 + nb * 512);
  }
  float bj[4], w0j[4];
#pragma unroll
  for (int nb = 0; nb < 4; ++nb) {
    int n = nb * 16 + l15;
    bj[nb] = bias[n];
    w0j[nb] = w[n * LIN];   // weight[:,0] fp32
  }

  __syncthreads();   // whole tile visible

  floatx4 acc[4][4];
#pragma unroll
  for (int mb = 0; mb < 4; ++mb)
#pragma unroll
    for (int nb = 0; nb < 4; ++nb) acc[mb][nb] = floatx4{0.f, 0.f, 0.f, 0.f};

#pragma unroll
  for (int step = 0; step < 18; ++step) {
    const int tap = step >> 1, half = step & 1;
    const int kh = tap / 3, kw = tap % 3;

    short8v bn[4];
    if (step + 3 < 18) {
#pragma unroll
      for (int nb = 0; nb < 4; ++nb)
        bn[nb] = *(const short8v*)(wfl + (step + 3) * 2048 + nb * 512);
    }

    const short* ab = &xt[((wv + kh) * 66 + kw + l15) * 72 + half * 32 + q * 8];
    short8v a[4];
#pragma unroll
    for (int mb = 0; mb < 4; ++mb)
      a[mb] = *(const short8v*)(ab + mb * 16 * 72);

#pragma unroll
    for (int mb = 0; mb < 4; ++mb) {
#pragma unroll
      for (int nb = 0; nb < 4; ++nb)
        acc[mb][nb] = __builtin_amdgcn_mfma_f32_16x16x32_bf16(a[mb], b0[nb], acc[mb][nb], 0, 0, 0);
    }
#pragma unroll
    for (int nb = 0; nb < 4; ++nb) { b0[nb] = b1[nb]; b1[nb] = b2[nb]; b2[nb] = bn[nb]; }
  }

  // ---- per-pixel time feature (this wave's row; lane <-> pixel col) ----
  {
    float ss = 0.f;
#pragma unroll
    for (int dh = 0; dh < 3; ++dh)
#pragma unroll
      for (int dw = 0; dw < 3; ++dw) {
        float tv = bf16_to_f32(xt[((wv + dh) * 66 + lane + dw) * 72]);
        tv = fmaxf(tv, 1.0f);
        ss += tv * tv;
      }
    tres_s[wv * 64 + lane] = sqrtf(ss - 8.0f);   // same-wave producer/consumer
  }

  __syncthreads();   // last xt read done (all waves) -> safe to alias as ostg

  // ---- epilogue: bias + rank-1 time term, Lorentz norm (DPP), scatter to LDS ----
  float* ostg = (float*)shmem + wv * 4160;   // this wave's 64px x 65ch row image
#pragma unroll
  for (int mb = 0; mb < 4; ++mb) {
    float4 t4 = *(const float4*)&tres_s[wv * 64 + mb * 16 + q * 4];
#pragma unroll
    for (int r = 0; r < 4; ++r) {
      int pcol = mb * 16 + q * 4 + r;      // C/D row m = quad*4 + reg
      float tr = t4[r];
      float v0 = acc[mb][0][r] + bj[0] + tr * w0j[0];
      float v1 = acc[mb][1][r] + bj[1] + tr * w0j[1];
      float v2 = acc[mb][2][r] + bj[2] + tr * w0j[2];
      float v3 = acc[mb][3][r] + bj[3] + tr * w0j[3];
      float ss = v0 * v0 + v1 * v1 + v2 * v2 + v3 * v3;
      ss = dpp_add<0xB1>(ss);    // + lane^1
      ss = dpp_add<0x4E>(ss);    // + lane^2
      ss = dpp_add<0x141>(ss);   // + mirror-8
      ss = dpp_add<0x140>(ss);   // + mirror-16 (full 16-lane sum)
      float* pb = ostg + pcol * 65;
      if (l15 == 0) pb[0] = sqrtf(ss + 1.0f);
      pb[1 + l15]  = v0;
      pb[17 + l15] = v1;
      pb[33 + l15] = v2;
      pb[49 + l15] = v3;
    }
  }

  // ---- coalesced flush: LDS row image -> global (dense dwordx4) ----
  // Same-wave produce/consume: compiler inserts the lgkmcnt wait; no barrier.
  {
    float* orow = out + (size_t)((bb * 64 + h0 + wv) * 64) * 65;
#pragma unroll
    for (int it = 0; it < 16; ++it) {
      int off = it * 256 + lane * 4;
      *(float4*)(orow + off) = *(const float4*)(ostg + off);
    }
    if (lane < 16) {   // remainder: 4160 - 4096 = 64 floats
      int off = 4096 + lane * 4;
      *(float4*)(orow + off) = *(const float4*)(ostg + off);
    }
  }
}

extern "C" void kernel_launch(void* const* d_in, const int* in_sizes, int n_in,
                              void* d_out, int out_size, void* d_ws, size_t ws_size,
                              hipStream_t stream) {
  const float* x = (const float*)d_in[0];
  const float* w = (const float*)d_in[1];
  const float* b = (const float*)d_in[2];
  float* out = (float*)d_out;
  short* wfragg = (short*)d_ws;   // 73728 B fragment-packed bf16 weight

  prep_weight<<<144, 256, 0, stream>>>(w, wfragg);
  lconv_main<<<32 * 16, 256, 0, stream>>>(x, w, b, wfragg, out);
}